// Round 4
// baseline (229.909 us; speedup 1.0000x reference)
//
#include <hip/hip_runtime.h>
#include <hip/hip_bf16.h>

// CapsuleLayer dynamic routing. B=64, I=2048, D=16, J=32, K=16, routings=3.
// Round 15: STRUCTURAL REWRITE — uhat (128MiB write + 3x128MiB read = 512MiB
// HBM, ~80% of runtime at ~3TB/s effective) is ELIMINATED. MfmaUtil was 3%:
// recompute u_hat per pass instead of re-reading it. Uses linearity
// b_t = u_hat . (v_0+..+v_{t-1}) = u_hat . vsum (already exploited before).
// Each pass reads x(8MiB) + W(64MiB, L3-resident after pass0) + writes 32MB
// f32 partials (into the freed uhat region). 3 passes + 3 squash reductions.
// Proven fragments reused verbatim from the 44.6us produce: W-stage LDS
// layout (j*384+k*24, bf16 pairs), zbuf zeroing of d=16..31 quads,
// mfma_f32_16x16x32_bf16 with C row=k(quad*4+r), col=b(l15).
// Per-block: 512 thr = 8 waves = 4 b-tiles x 2 j-halves; j-half split keeps
// per-lane acc at 16j x 4k = 64 VGPR. Softmax: per-lane p[16] over own
// j-half, denominator halves exchanged via 1KB LDS ebuf (1 barrier).
// Lessons kept: never force min-waves; bf16 operand rounding unchanged
// (absmax should be <= 0.00488 — u_hat now consumed at MFMA f32 precision).

#define B_ 64
#define I_ 2048
#define D_ 16
#define J_ 32
#define K_ 16
#define JK 512  // J_*K_
#define NBLK 256  // fused-pass grid; partials = NBLK * 128KB = 32MB
#define GI 8      // i's per block (NBLK * GI == I_)

typedef __attribute__((ext_vector_type(8))) short short8;
typedef __attribute__((ext_vector_type(4))) float float4v;

__device__ __forceinline__ unsigned short f2bf(float f) {
    union { float f; unsigned int i; } v;
    v.f = f;
    const unsigned int x = v.i;
    return (unsigned short)((x + 0x7fffu + ((x >> 16) & 1u)) >> 16);  // RNE
}

// ---------------------------------------------------------------------------
// Fused routing pass. MODE 0: uniform c (round 0) — acc += u_hat, no softmax.
// MODE 1: acc += softmax_j(u_hat . vsum) * u_hat.
// Grid NBLK x 512. Wave wv: bt = wv&3 (b-tile of 16), jh = wv>>2 (j-half).
// Per lane (l15, quad): b = bt*16+l15; MFMA j gives u_hat[b][j][quad*4+r].
// ---------------------------------------------------------------------------
template <int MODE>
__global__ __launch_bounds__(512)
void caps_pass(const float* __restrict__ x, const float* __restrict__ W,
               const float* __restrict__ vsum, float* __restrict__ part) {
    __shared__ unsigned short wlds[2][32 * 384];  // 48 KB double-buffered W
    __shared__ unsigned short zbuf[8];            // zeros for d=16..31 quads
    __shared__ float ebuf[2][4][2][16];           // per-half exp-sum exchange
    const int tid = threadIdx.x;
    const int lane = tid & 63;
    const int wv = tid >> 6;   // 0..7
    const int bt = wv & 3;     // b-tile index
    const int jh = wv >> 2;    // j-half index
    const int quad = lane >> 4;
    const int l15 = lane & 15;
    const int b = bt * 16 + l15;
    const int i0 = blockIdx.x * GI;

    if (tid < 8) zbuf[tid] = 0;

    // vsum fragment: vv[jj] = vsum[b][jh*16+jj][quad*4 .. +3] (MODE 1 only)
    float4 vv[16];
    if (MODE == 1) {
#pragma unroll
        for (int jj = 0; jj < 16; ++jj)
            vv[jj] = reinterpret_cast<const float4*>(
                vsum + b * JK + (jh * 16 + jj) * 16 + quad * 4)[0];
    }

    float4 acc2[16];
#pragma unroll
    for (int jj = 0; jj < 16; ++jj) {
        acc2[jj].x = 0.f; acc2[jj].y = 0.f;
        acc2[jj].z = 0.f; acc2[jj].w = 0.f;
    }

    const int sk = tid & 15;   // stage: k lane
    const int sj = tid >> 4;   // stage: j row 0..31 (512 threads cover all)

    for (int t = 0; t < GI; ++t) {
        const int i = i0 + t;
        const int par = t & 1;

        // ---- stage W[i] -> wlds[par] (proven produce layout) ----
        {
            const float* p = W + (size_t)i * (J_ * D_ * K_) + sj * (D_ * K_) + sk;
            float vals[16];
#pragma unroll
            for (int d = 0; d < 16; ++d) vals[d] = p[d * K_];
            unsigned int pk[8];
#pragma unroll
            for (int q = 0; q < 8; ++q)
                pk[q] = ((unsigned int)f2bf(vals[2 * q + 1]) << 16) |
                        f2bf(vals[2 * q]);
            uint4* dst = reinterpret_cast<uint4*>(&wlds[par][sj * 384 + sk * 24]);
            uint4 w0; w0.x = pk[0]; w0.y = pk[1]; w0.z = pk[2]; w0.w = pk[3];
            uint4 w1; w1.x = pk[4]; w1.y = pk[5]; w1.z = pk[6]; w1.w = pk[7];
            dst[0] = w0; dst[1] = w1;
        }

        // ---- x bfrag for this i (proven produce code) ----
        union { uint4 u; short8 s; } bfrag;
        {
            const float* xp = x + ((size_t)b * I_ + i) * D_ + (quad & 1) * 8;
            const float4 x0 = reinterpret_cast<const float4*>(xp)[0];
            const float4 x1 = reinterpret_cast<const float4*>(xp)[1];
            bfrag.u.x = ((unsigned int)f2bf(x0.y) << 16) | f2bf(x0.x);
            bfrag.u.y = ((unsigned int)f2bf(x0.w) << 16) | f2bf(x0.z);
            bfrag.u.z = ((unsigned int)f2bf(x1.y) << 16) | f2bf(x1.x);
            bfrag.u.w = ((unsigned int)f2bf(x1.w) << 16) | f2bf(x1.z);
            if (quad >= 2) { bfrag.u.x = 0; bfrag.u.y = 0; bfrag.u.z = 0; bfrag.u.w = 0; }
        }
        __syncthreads();  // wlds[par] ready

        const unsigned short* aptr =
            (quad >= 2) ? zbuf : (&wlds[par][0] + l15 * 24 + (quad & 1) * 8);
        const int astride = (quad >= 2) ? 0 : 384;

        if (MODE == 0) {
            // uniform-c pass: acc += u_hat (1/32 scale applied in squash)
#pragma unroll
            for (int jj = 0; jj < 16; ++jj) {
                const int j = jh * 16 + jj;
                union { uint4 u; short8 s; } af;
                af.u = *reinterpret_cast<const uint4*>(aptr + (size_t)j * astride);
                float4v a = {0.f, 0.f, 0.f, 0.f};
                a = __builtin_amdgcn_mfma_f32_16x16x32_bf16(af.s, bfrag.s, a,
                                                            0, 0, 0);
                acc2[jj].x += a[0]; acc2[jj].y += a[1];
                acc2[jj].z += a[2]; acc2[jj].w += a[3];
            }
            // 1 barrier/iter is safe: next stage writes wlds[par^1]; a wave
            // can only reach stage of par again after passing the next
            // barrier, which requires all waves done reading wlds[par].
        } else {
            // sweep 1: p[b,j] = sum_k u_hat*vsum, then exp + half-denominator
            float e[16];
            float E = 0.f;
#pragma unroll
            for (int jj = 0; jj < 16; ++jj) {
                const int j = jh * 16 + jj;
                union { uint4 u; short8 s; } af;
                af.u = *reinterpret_cast<const uint4*>(aptr + (size_t)j * astride);
                float4v a = {0.f, 0.f, 0.f, 0.f};
                a = __builtin_amdgcn_mfma_f32_16x16x32_bf16(af.s, bfrag.s, a,
                                                            0, 0, 0);
                float p = a[0] * vv[jj].x + a[1] * vv[jj].y +
                          a[2] * vv[jj].z + a[3] * vv[jj].w;
                p += __shfl_xor(p, 16, 64);  // cross-quad k-reduce
                p += __shfl_xor(p, 32, 64);
                const float ee = __expf(p);  // |p| bounded; f32-safe
                e[jj] = ee;
                E += ee;
            }
            if (quad == 0) ebuf[par][bt][jh][l15] = E;
            __syncthreads();  // ebuf[par] ready (dbuf'd by parity)
            const float S = E + ebuf[par][bt][1 - jh][l15];
            const float r = __builtin_amdgcn_rcpf(S);
            // sweep 2: recompute u_hat (MFMA is ~3% utilized — cheaper than
            // 64 more VGPRs), accumulate c * u_hat
#pragma unroll
            for (int jj = 0; jj < 16; ++jj) {
                const int j = jh * 16 + jj;
                union { uint4 u; short8 s; } af;
                af.u = *reinterpret_cast<const uint4*>(aptr + (size_t)j * astride);
                float4v a = {0.f, 0.f, 0.f, 0.f};
                a = __builtin_amdgcn_mfma_f32_16x16x32_bf16(af.s, bfrag.s, a,
                                                            0, 0, 0);
                const float c = e[jj] * r;
                acc2[jj].x += c * a[0]; acc2[jj].y += c * a[1];
                acc2[jj].z += c * a[2]; acc2[jj].w += c * a[3];
            }
        }
    }

    // ---- store partial [blk][b][j][k] (f32, contiguous per lane-slice) ----
    float* pp = part + ((size_t)blockIdx.x * B_ + b) * JK + jh * 256 + quad * 4;
#pragma unroll
    for (int jj = 0; jj < 16; ++jj)
        reinterpret_cast<float4*>(pp + jj * 16)[0] = acc2[jj];
}

// ---------------------------------------------------------------------------
// Reduce NBLK partials + squash. MODE 0: vsum = squash(s/32).
// MODE 1: vsum += squash(s).  MODE 2: out = squash(s).
// ---------------------------------------------------------------------------
template <int MODE>
__global__ __launch_bounds__(512)
void caps_squashN(const float* __restrict__ part, float* __restrict__ vsum,
                  float* __restrict__ out) {
    const int bl = blockIdx.x;
    const int jk = threadIdx.x;
    float s = 0.f;
#pragma unroll 8
    for (int p = 0; p < NBLK; ++p)
        s += part[((size_t)p * B_ + bl) * JK + jk];
    if (MODE == 0) s *= (1.f / 32.f);
    float q = s * s;
    q += __shfl_xor(q, 1, 64);
    q += __shfl_xor(q, 2, 64);
    q += __shfl_xor(q, 4, 64);
    q += __shfl_xor(q, 8, 64);
    const float scale = q / ((1.f + q) * sqrtf(q + 1e-7f));
    const float v = scale * s;
    if (MODE == 0)      vsum[bl * JK + jk] = v;
    else if (MODE == 1) vsum[bl * JK + jk] += v;
    else                out[(size_t)bl * JK + jk] = v;
}

// ---------------------------------------------------------------------------
extern "C" void kernel_launch(void* const* d_in, const int* in_sizes, int n_in,
                              void* d_out, int out_size, void* d_ws,
                              size_t ws_size, hipStream_t stream) {
    const float* x = (const float*)d_in[0];  // [B,I,D] f32
    const float* W = (const float*)d_in[1];  // [I,J,D,K] f32
    float* out = (float*)d_out;              // [B,J,K] f32

    char* ws = (char*)d_ws;
    // partials live in the region uhat used to occupy (32 MB of 128 MiB)
    float* part = (float*)ws;
    // vsum keeps its proven offset at the tail of the workspace
    float* vsum =
        (float*)(ws + (size_t)B_ * I_ * JK * 2 + (size_t)64 * B_ * JK * 4);

    // round 0: uniform c = 1/32
    caps_pass<0><<<NBLK, 512, 0, stream>>>(x, W, nullptr, part);
    caps_squashN<0><<<B_, 512, 0, stream>>>(part, vsum, nullptr);
    // round 1
    caps_pass<1><<<NBLK, 512, 0, stream>>>(x, W, vsum, part);
    caps_squashN<1><<<B_, 512, 0, stream>>>(part, vsum, nullptr);
    // round 2
    caps_pass<1><<<NBLK, 512, 0, stream>>>(x, W, vsum, part);
    caps_squashN<2><<<B_, 512, 0, stream>>>(part, vsum, out);
}

// Round 5
// 191.511 us; speedup vs baseline: 1.2005x; 1.2005x over previous
//
#include <hip/hip_runtime.h>
#include <hip/hip_bf16.h>

// CapsuleLayer dynamic routing. B=64, I=2048, D=16, J=32, K=16, routings=3.
// Structure (round 15): uhat eliminated (was 512MiB HBM traffic); each pass
// recomputes u_hat via MFMA using b_t = u_hat . vsum linearity. Pass reads
// x(8MiB)+W(64MiB)+writes 32MB f32 partials; 3 passes + 3 squash reductions.
// Round-15 post-mortem: passes ~40us (no real pipelining: stage->barrier->
// compute exposes W-load latency at 2 waves/SIMD), squashN ~20-35us (64
// blocks = 3/4 of chip idle). absmax improved to 0.0039 (u_hat consumed at
// MFMA f32 precision).
// Round 16:
//  - caps_pass: register-prefetch W[i+1] (16 f32) + x[i+1] (2 float4) BEFORE
//    the barrier of iter t; pack+ds_write AFTER compute into buf p^1.
//    Safety: writes to p^1 at t follow B1_t; all reads of p^1 (iter t-1)
//    precede B1_t in program order. No extra barriers.
//  - caps_squashN: grid 64 -> 256 blocks (B x 4 jk-quarters) x 512 thr,
//    4-way p-split + LDS merge -> 8 waves/CU.
// Lessons kept: never force min-waves (r8 spill); ctile staging mandatory
// for any scattered global store (r13); W-stage LDS layout j*384+k*24 and
// MFMA C-layout row=k(quad*4+r), col=b(l15) proven in the 44us produce.

#define B_ 64
#define I_ 2048
#define D_ 16
#define J_ 32
#define K_ 16
#define JK 512    // J_*K_
#define NBLK 256  // fused-pass grid; partials = NBLK * 128KB = 32MB
#define GI 8      // i's per block (NBLK * GI == I_)

typedef __attribute__((ext_vector_type(8))) short short8;
typedef __attribute__((ext_vector_type(4))) float float4v;

__device__ __forceinline__ unsigned short f2bf(float f) {
    union { float f; unsigned int i; } v;
    v.f = f;
    const unsigned int x = v.i;
    return (unsigned short)((x + 0x7fffu + ((x >> 16) & 1u)) >> 16);  // RNE
}

// ---------------------------------------------------------------------------
// Fused routing pass. MODE 0: uniform c (round 0) — acc += u_hat, no softmax.
// MODE 1: acc += softmax_j(u_hat . vsum) * u_hat.
// Grid NBLK x 512. Wave wv: bt = wv&3 (b-tile of 16), jh = wv>>2 (j-half).
// Per lane (l15, quad): b = bt*16+l15; MFMA j gives u_hat[b][j][quad*4+r].
// ---------------------------------------------------------------------------
template <int MODE>
__global__ __launch_bounds__(512)
void caps_pass(const float* __restrict__ x, const float* __restrict__ W,
               const float* __restrict__ vsum, float* __restrict__ part) {
    __shared__ unsigned short wlds[2][32 * 384];  // 48 KB double-buffered W
    __shared__ unsigned short zbuf[8];            // zeros for d=16..31 quads
    __shared__ float ebuf[2][4][2][16];           // per-half exp-sum exchange
    const int tid = threadIdx.x;
    const int lane = tid & 63;
    const int wv = tid >> 6;   // 0..7
    const int bt = wv & 3;     // b-tile index
    const int jh = wv >> 2;    // j-half index
    const int quad = lane >> 4;
    const int l15 = lane & 15;
    const int b = bt * 16 + l15;
    const int i0 = blockIdx.x * GI;

    if (tid < 8) zbuf[tid] = 0;

    // vsum fragment: vv[jj] = vsum[b][jh*16+jj][quad*4 .. +3] (MODE 1 only)
    float4 vv[16];
    if (MODE == 1) {
#pragma unroll
        for (int jj = 0; jj < 16; ++jj)
            vv[jj] = reinterpret_cast<const float4*>(
                vsum + b * JK + (jh * 16 + jj) * 16 + quad * 4)[0];
    }

    float4 acc2[16];
#pragma unroll
    for (int jj = 0; jj < 16; ++jj) {
        acc2[jj].x = 0.f; acc2[jj].y = 0.f;
        acc2[jj].z = 0.f; acc2[jj].w = 0.f;
    }

    const int sk = tid & 15;   // stage: k lane
    const int sj = tid >> 4;   // stage: j row 0..31 (512 threads cover all)
    const float* wp = W + (size_t)i0 * (J_ * D_ * K_) + sj * (D_ * K_) + sk;
    const float* xp = x + ((size_t)b * I_ + i0) * D_ + (quad & 1) * 8;

    // ---- prologue: load i0's W and x into registers, stage buf 0 ----
    float vals[16];
#pragma unroll
    for (int d = 0; d < 16; ++d) vals[d] = wp[d * K_];
    float4 xr0 = reinterpret_cast<const float4*>(xp)[0];
    float4 xr1 = reinterpret_cast<const float4*>(xp)[1];
    {
        unsigned int pk[8];
#pragma unroll
        for (int q = 0; q < 8; ++q)
            pk[q] = ((unsigned int)f2bf(vals[2 * q + 1]) << 16) |
                    f2bf(vals[2 * q]);
        uint4* dst = reinterpret_cast<uint4*>(&wlds[0][sj * 384 + sk * 24]);
        uint4 w0; w0.x = pk[0]; w0.y = pk[1]; w0.z = pk[2]; w0.w = pk[3];
        uint4 w1; w1.x = pk[4]; w1.y = pk[5]; w1.z = pk[6]; w1.w = pk[7];
        dst[0] = w0; dst[1] = w1;
    }

    for (int t = 0; t < GI; ++t) {
        const int p = t & 1;

        // pack current x frag (registers already loaded)
        union { uint4 u; short8 s; } bfrag;
        bfrag.u.x = ((unsigned int)f2bf(xr0.y) << 16) | f2bf(xr0.x);
        bfrag.u.y = ((unsigned int)f2bf(xr0.w) << 16) | f2bf(xr0.z);
        bfrag.u.z = ((unsigned int)f2bf(xr1.y) << 16) | f2bf(xr1.x);
        bfrag.u.w = ((unsigned int)f2bf(xr1.w) << 16) | f2bf(xr1.z);
        if (quad >= 2) { bfrag.u.x = 0; bfrag.u.y = 0; bfrag.u.z = 0; bfrag.u.w = 0; }

        // ---- prefetch i_{t+1}: issue global loads NOW, consume after
        //      compute (latency hidden under 32 MFMAs + softmax VALU) ----
        float nv[16];
        float4 nx0, nx1;
        if (t < GI - 1) {
            const float* wn = wp + (size_t)(t + 1) * (J_ * D_ * K_);
#pragma unroll
            for (int d = 0; d < 16; ++d) nv[d] = wn[d * K_];
            const float* xn = xp + (t + 1) * D_;
            nx0 = reinterpret_cast<const float4*>(xn)[0];
            nx1 = reinterpret_cast<const float4*>(xn)[1];
        }

        __syncthreads();  // B1: wlds[p] (written end of prev iter) ready

        const unsigned short* aptr =
            (quad >= 2) ? zbuf : (&wlds[p][0] + l15 * 24 + (quad & 1) * 8);
        const int astride = (quad >= 2) ? 0 : 384;

        if (MODE == 0) {
            // uniform-c pass: acc += u_hat (1/32 scale applied in squash)
#pragma unroll
            for (int jj = 0; jj < 16; ++jj) {
                const int j = jh * 16 + jj;
                union { uint4 u; short8 s; } af;
                af.u = *reinterpret_cast<const uint4*>(aptr + (size_t)j * astride);
                float4v a = {0.f, 0.f, 0.f, 0.f};
                a = __builtin_amdgcn_mfma_f32_16x16x32_bf16(af.s, bfrag.s, a,
                                                            0, 0, 0);
                acc2[jj].x += a[0]; acc2[jj].y += a[1];
                acc2[jj].z += a[2]; acc2[jj].w += a[3];
            }
        } else {
            // sweep 1: p[b,j] = sum_k u_hat*vsum, exp, half-denominator
            float e[16];
            float E = 0.f;
#pragma unroll
            for (int jj = 0; jj < 16; ++jj) {
                const int j = jh * 16 + jj;
                union { uint4 u; short8 s; } af;
                af.u = *reinterpret_cast<const uint4*>(aptr + (size_t)j * astride);
                float4v a = {0.f, 0.f, 0.f, 0.f};
                a = __builtin_amdgcn_mfma_f32_16x16x32_bf16(af.s, bfrag.s, a,
                                                            0, 0, 0);
                float pj = a[0] * vv[jj].x + a[1] * vv[jj].y +
                           a[2] * vv[jj].z + a[3] * vv[jj].w;
                pj += __shfl_xor(pj, 16, 64);  // cross-quad k-reduce
                pj += __shfl_xor(pj, 32, 64);
                const float ee = __expf(pj);  // |p| bounded; f32-safe
                e[jj] = ee;
                E += ee;
            }
            if (quad == 0) ebuf[p][bt][jh][l15] = E;
            __syncthreads();  // B2: ebuf[p] ready (parity-dbuf'd)
            const float S = E + ebuf[p][bt][1 - jh][l15];
            const float r = __builtin_amdgcn_rcpf(S);
            // sweep 2: re-MFMA u_hat (MFMA ~3% utilized — cheaper than 64
            // more VGPRs), accumulate c * u_hat
#pragma unroll
            for (int jj = 0; jj < 16; ++jj) {
                const int j = jh * 16 + jj;
                union { uint4 u; short8 s; } af;
                af.u = *reinterpret_cast<const uint4*>(aptr + (size_t)j * astride);
                float4v a = {0.f, 0.f, 0.f, 0.f};
                a = __builtin_amdgcn_mfma_f32_16x16x32_bf16(af.s, bfrag.s, a,
                                                            0, 0, 0);
                const float c = e[jj] * r;
                acc2[jj].x += c * a[0]; acc2[jj].y += c * a[1];
                acc2[jj].z += c * a[2]; acc2[jj].w += c * a[3];
            }
        }

        // ---- consume prefetch: pack + stage into wlds[p^1] ----
        // Safe: all reads of wlds[p^1] (iter t-1) precede B1_t in program
        // order; next reads happen after B1_{t+1}.
        if (t < GI - 1) {
            unsigned int pk[8];
#pragma unroll
            for (int q = 0; q < 8; ++q)
                pk[q] = ((unsigned int)f2bf(nv[2 * q + 1]) << 16) |
                        f2bf(nv[2 * q]);
            uint4* dst =
                reinterpret_cast<uint4*>(&wlds[p ^ 1][sj * 384 + sk * 24]);
            uint4 w0; w0.x = pk[0]; w0.y = pk[1]; w0.z = pk[2]; w0.w = pk[3];
            uint4 w1; w1.x = pk[4]; w1.y = pk[5]; w1.z = pk[6]; w1.w = pk[7];
            dst[0] = w0; dst[1] = w1;
            xr0 = nx0; xr1 = nx1;
        }
    }

    // ---- store partial [blk][b][j][k] (f32, contiguous per lane-slice) ----
    float* pp = part + ((size_t)blockIdx.x * B_ + b) * JK + jh * 256 + quad * 4;
#pragma unroll
    for (int jj = 0; jj < 16; ++jj)
        reinterpret_cast<float4*>(pp + jj * 16)[0] = acc2[jj];
}

// ---------------------------------------------------------------------------
// Reduce NBLK partials + squash. Grid B_*4 (jk quarters) x 512 threads;
// h = tid>>7 splits the p-range 4 ways, merged through LDS.
// MODE 0: vsum = squash(s/32). MODE 1: vsum += squash(s). MODE 2: out = ...
// ---------------------------------------------------------------------------
template <int MODE>
__global__ __launch_bounds__(512)
void caps_squashN(const float* __restrict__ part, float* __restrict__ vsum,
                  float* __restrict__ out) {
    __shared__ float red[3][128];
    const int bl = blockIdx.x >> 2;
    const int q4 = blockIdx.x & 3;
    const int jk128 = threadIdx.x & 127;
    const int h = threadIdx.x >> 7;  // 0..3
    const int jk = q4 * 128 + jk128;

    float s = 0.f;
#pragma unroll 8
    for (int p = h * (NBLK / 4); p < (h + 1) * (NBLK / 4); ++p)
        s += part[((size_t)p * B_ + bl) * JK + jk];

    if (h > 0) red[h - 1][jk128] = s;
    __syncthreads();
    if (h == 0) {
        s += red[0][jk128] + red[1][jk128] + red[2][jk128];
        if (MODE == 0) s *= (1.f / 32.f);
        float qq = s * s;
        qq += __shfl_xor(qq, 1, 64);
        qq += __shfl_xor(qq, 2, 64);
        qq += __shfl_xor(qq, 4, 64);
        qq += __shfl_xor(qq, 8, 64);
        const float scale = qq / ((1.f + qq) * sqrtf(qq + 1e-7f));
        const float v = scale * s;
        if (MODE == 0)      vsum[bl * JK + jk] = v;
        else if (MODE == 1) vsum[bl * JK + jk] += v;
        else                out[(size_t)bl * JK + jk] = v;
    }
}

// ---------------------------------------------------------------------------
extern "C" void kernel_launch(void* const* d_in, const int* in_sizes, int n_in,
                              void* d_out, int out_size, void* d_ws,
                              size_t ws_size, hipStream_t stream) {
    const float* x = (const float*)d_in[0];  // [B,I,D] f32
    const float* W = (const float*)d_in[1];  // [I,J,D,K] f32
    float* out = (float*)d_out;              // [B,J,K] f32

    char* ws = (char*)d_ws;
    // partials live in the region uhat used to occupy (32 MB of 128 MiB)
    float* part = (float*)ws;
    // vsum keeps its proven offset at the tail of the workspace
    float* vsum =
        (float*)(ws + (size_t)B_ * I_ * JK * 2 + (size_t)64 * B_ * JK * 4);

    // round 0: uniform c = 1/32
    caps_pass<0><<<NBLK, 512, 0, stream>>>(x, W, nullptr, part);
    caps_squashN<0><<<B_ * 4, 512, 0, stream>>>(part, vsum, nullptr);
    // round 1
    caps_pass<1><<<NBLK, 512, 0, stream>>>(x, W, vsum, part);
    caps_squashN<1><<<B_ * 4, 512, 0, stream>>>(part, vsum, nullptr);
    // round 2
    caps_pass<1><<<NBLK, 512, 0, stream>>>(x, W, vsum, part);
    caps_squashN<2><<<B_ * 4, 512, 0, stream>>>(part, vsum, out);
}